// Round 1
// baseline (1878.374 us; speedup 1.0000x reference)
//
#include <hip/hip_runtime.h>
#include <hip/hip_bf16.h>
#include <cstdint>
#include <cstddef>

// Problem constants
#define T_TOK 2048
#define HDIM  2048
#define FDIM  5632
#define NEXP  8
#define KTOP  2
#define NPAIR (T_TOK * KTOP)     // 4096 (token,expert) pairs total
#define ROWCAP (NPAIR + 128)     // slack so row tiles can over-read safely

#define LDSTRIDE 40              // padded LDS row stride in bf16 elements (32 data + 8 pad)

typedef unsigned short u16;
typedef __attribute__((ext_vector_type(8))) short short8;   // 8 bf16 = 4 VGPRs (MFMA A/B frag)
typedef __attribute__((ext_vector_type(4))) float floatx4;  // MFMA C/D frag

__device__ __forceinline__ u16 f2bf(float f) {
  unsigned u = __float_as_uint(f);
  u += 0x7fffu + ((u >> 16) & 1u);   // round-to-nearest-even
  return (u16)(u >> 16);
}

__device__ __forceinline__ uint4 cvt8(const float4 a, const float4 b) {
  uint4 r;
  r.x = (unsigned)f2bf(a.x) | ((unsigned)f2bf(a.y) << 16);
  r.y = (unsigned)f2bf(a.z) | ((unsigned)f2bf(a.w) << 16);
  r.z = (unsigned)f2bf(b.x) | ((unsigned)f2bf(b.y) << 16);
  r.w = (unsigned)f2bf(b.z) | ((unsigned)f2bf(b.w) << 16);
  return r;
}

// ---------------- routing: counts, offsets, scatter ----------------
__global__ void route_kernel(const float* __restrict__ rw, const int* __restrict__ sel,
                             int* __restrict__ cnt, int* __restrict__ offs,
                             int* __restrict__ tok, float* __restrict__ tokw) {
  __shared__ int scnt[NEXP], soff[NEXP], scur[NEXP];
  int t = threadIdx.x;
  if (t < NEXP) scnt[t] = 0;
  __syncthreads();
  for (int p = t; p < NPAIR; p += 256) atomicAdd(&scnt[sel[p]], 1);
  __syncthreads();
  if (t == 0) {
    int a = 0;
    for (int e = 0; e < NEXP; ++e) { soff[e] = a; scur[e] = a; a += scnt[e]; }
  }
  __syncthreads();
  for (int p = t; p < NPAIR; p += 256) {
    int e = sel[p];
    int pos = atomicAdd(&scur[e], 1);
    tok[pos]  = p >> 1;          // K=2: token index
    tokw[pos] = rw[p];
  }
  if (t < NEXP) { cnt[t] = scnt[t]; offs[t] = soff[t]; }
}

// ---------------- gather hidden rows -> compact bf16 A ----------------
__global__ void gather_kernel(const float* __restrict__ hs, const int* __restrict__ tok,
                              u16* __restrict__ Xg) {
  int row = blockIdx.x;
  int t = tok[row];
  const float4* src = (const float4*)(hs + (size_t)t * HDIM);
  int i = threadIdx.x;              // 256 threads * 8 floats = 2048
  float4 a = src[2 * i], b = src[2 * i + 1];
  *(uint4*)&Xg[(size_t)row * HDIM + 8 * i] = cvt8(a, b);
}

// ---------------- GEMM1: Xg @ W1[e]^T (gate+up paired), silu fuse -> g ----------------
__global__ __launch_bounds__(256, 2) void gemm1_kernel(
    const u16* __restrict__ Xg, const float* __restrict__ W1,
    u16* __restrict__ gbuf, const int* __restrict__ cnt, const int* __restrict__ offs) {
  int e = blockIdx.z;
  int cnt_e = cnt[e];
  int rb = blockIdx.y;
  if (rb * 128 >= cnt_e) return;
  int row0 = offs[e] + rb * 128;          // compacted global row base
  int n0 = blockIdx.x * 128;              // gate column base in [0,F)

  const float* W1e = W1 + (size_t)e * (2 * FDIM) * HDIM;

  __shared__ u16 As[128 * LDSTRIDE];
  __shared__ u16 Bg[128 * LDSTRIDE];
  __shared__ u16 Bu[128 * LDSTRIDE];

  int tid = threadIdx.x;
  int lane = tid & 63;
  int w = tid >> 6;
  int wr = w >> 1, wc = w & 1;            // 2x2 wave grid, 64x64 per wave

  floatx4 zero4 = {0.f, 0.f, 0.f, 0.f};
  floatx4 accg[4][4], accu[4][4];
#pragma unroll
  for (int i = 0; i < 4; ++i)
#pragma unroll
    for (int j = 0; j < 4; ++j) { accg[i][j] = zero4; accu[i][j] = zero4; }

  // staging assignment: thread -> (row sr, half sh); 16 elements per thread per tile
  int sr = tid >> 1;       // 0..127
  int sh = tid & 1;        // 0..1
  const u16*   aSrc = Xg  + (size_t)(row0 + sr) * HDIM + sh * 16;
  const float* bgSrc = W1e + (size_t)(n0 + sr) * HDIM + sh * 16;
  const float* buSrc = W1e + (size_t)(FDIM + n0 + sr) * HDIM + sh * 16;
  u16* aDst = &As[sr * LDSTRIDE + sh * 16];
  u16* bgDst = &Bg[sr * LDSTRIDE + sh * 16];
  u16* buDst = &Bu[sr * LDSTRIDE + sh * 16];

  // fragment read offsets (element units)
  int aOff = (wr * 64 + (lane & 15)) * LDSTRIDE + (lane >> 4) * 8;
  int bOff = (wc * 64 + (lane & 15)) * LDSTRIDE + (lane >> 4) * 8;

  for (int kt = 0; kt < HDIM / 32; ++kt) {
    __syncthreads();
    // stage A (bf16 copy)
    const uint4* pa = (const uint4*)(aSrc + kt * 32);
    uint4 a0 = pa[0], a1 = pa[1];
    // stage B gate (fp32 -> bf16)
    const float4* pg = (const float4*)(bgSrc + kt * 32);
    float4 g0 = pg[0], g1 = pg[1], g2 = pg[2], g3 = pg[3];
    const float4* pu = (const float4*)(buSrc + kt * 32);
    float4 u0 = pu[0], u1 = pu[1], u2 = pu[2], u3 = pu[3];
    *(uint4*)(aDst) = a0;
    *(uint4*)(aDst + 8) = a1;
    *(uint4*)(bgDst) = cvt8(g0, g1);
    *(uint4*)(bgDst + 8) = cvt8(g2, g3);
    *(uint4*)(buDst) = cvt8(u0, u1);
    *(uint4*)(buDst + 8) = cvt8(u2, u3);
    __syncthreads();

    short8 af[4];
#pragma unroll
    for (int i = 0; i < 4; ++i)
      af[i] = *(const short8*)&As[aOff + i * 16 * LDSTRIDE];
#pragma unroll
    for (int j = 0; j < 4; ++j) {
      short8 bgf = *(const short8*)&Bg[bOff + j * 16 * LDSTRIDE];
      short8 buf2 = *(const short8*)&Bu[bOff + j * 16 * LDSTRIDE];
#pragma unroll
      for (int i = 0; i < 4; ++i) {
        accg[i][j] = __builtin_amdgcn_mfma_f32_16x16x32_bf16(af[i], bgf, accg[i][j], 0, 0, 0);
        accu[i][j] = __builtin_amdgcn_mfma_f32_16x16x32_bf16(af[i], buf2, accu[i][j], 0, 0, 0);
      }
    }
  }

  // epilogue: g = silu(gate) * up, store bf16, mask rows >= cnt_e
#pragma unroll
  for (int i = 0; i < 4; ++i) {
#pragma unroll
    for (int r = 0; r < 4; ++r) {
      int row_l = wr * 64 + i * 16 + (lane >> 4) * 4 + r;
      int lrow = rb * 128 + row_l;
      if (lrow < cnt_e) {
        size_t grow = (size_t)(row0 + row_l);
#pragma unroll
        for (int j = 0; j < 4; ++j) {
          int col = n0 + wc * 64 + j * 16 + (lane & 15);
          float gv = accg[i][j][r];
          float uv = accu[i][j][r];
          float s = gv / (1.0f + __expf(-gv));
          gbuf[grow * FDIM + col] = f2bf(s * uv);
        }
      }
    }
  }
}

// ---------------- GEMM2: g @ W2[e]^T, scale by routing weight, atomic scatter ----------------
__global__ __launch_bounds__(256, 2) void gemm2_kernel(
    const u16* __restrict__ gbuf, const float* __restrict__ W2, float* __restrict__ out,
    const int* __restrict__ cnt, const int* __restrict__ offs,
    const int* __restrict__ tok, const float* __restrict__ tokw) {
  int e = blockIdx.z;
  int cnt_e = cnt[e];
  int rb = blockIdx.y;
  if (rb * 128 >= cnt_e) return;
  int row0 = offs[e] + rb * 128;
  int n0 = blockIdx.x * 128;              // output (H) column base

  const float* W2e = W2 + (size_t)e * HDIM * FDIM;

  __shared__ u16 As[128 * LDSTRIDE];
  __shared__ u16 Bs[128 * LDSTRIDE];

  int tid = threadIdx.x;
  int lane = tid & 63;
  int w = tid >> 6;
  int wr = w >> 1, wc = w & 1;

  floatx4 zero4 = {0.f, 0.f, 0.f, 0.f};
  floatx4 acc[4][4];
#pragma unroll
  for (int i = 0; i < 4; ++i)
#pragma unroll
    for (int j = 0; j < 4; ++j) acc[i][j] = zero4;

  int sr = tid >> 1;
  int sh = tid & 1;
  const u16*   aSrc = gbuf + (size_t)(row0 + sr) * FDIM + sh * 16;
  const float* bSrc = W2e + (size_t)(n0 + sr) * FDIM + sh * 16;
  u16* aDst = &As[sr * LDSTRIDE + sh * 16];
  u16* bDst = &Bs[sr * LDSTRIDE + sh * 16];

  int aOff = (wr * 64 + (lane & 15)) * LDSTRIDE + (lane >> 4) * 8;
  int bOff = (wc * 64 + (lane & 15)) * LDSTRIDE + (lane >> 4) * 8;

  for (int kt = 0; kt < FDIM / 32; ++kt) {
    __syncthreads();
    const uint4* pa = (const uint4*)(aSrc + kt * 32);
    uint4 a0 = pa[0], a1 = pa[1];
    const float4* pb = (const float4*)(bSrc + kt * 32);
    float4 b0 = pb[0], b1 = pb[1], b2 = pb[2], b3 = pb[3];
    *(uint4*)(aDst) = a0;
    *(uint4*)(aDst + 8) = a1;
    *(uint4*)(bDst) = cvt8(b0, b1);
    *(uint4*)(bDst + 8) = cvt8(b2, b3);
    __syncthreads();

    short8 af[4];
#pragma unroll
    for (int i = 0; i < 4; ++i)
      af[i] = *(const short8*)&As[aOff + i * 16 * LDSTRIDE];
#pragma unroll
    for (int j = 0; j < 4; ++j) {
      short8 bf = *(const short8*)&Bs[bOff + j * 16 * LDSTRIDE];
#pragma unroll
      for (int i = 0; i < 4; ++i)
        acc[i][j] = __builtin_amdgcn_mfma_f32_16x16x32_bf16(af[i], bf, acc[i][j], 0, 0, 0);
    }
  }

#pragma unroll
  for (int i = 0; i < 4; ++i) {
#pragma unroll
    for (int r = 0; r < 4; ++r) {
      int row_l = wr * 64 + i * 16 + (lane >> 4) * 4 + r;
      int lrow = rb * 128 + row_l;
      if (lrow >= cnt_e) continue;
      int grow = row0 + row_l;
      int t = tok[grow];
      float wgt = tokw[grow];
      float* orow = out + (size_t)t * HDIM + n0 + wc * 64 + (lane & 15);
#pragma unroll
      for (int j = 0; j < 4; ++j)
        atomicAdd(orow + j * 16, acc[i][j][r] * wgt);
    }
  }
}

extern "C" void kernel_launch(void* const* d_in, const int* in_sizes, int n_in,
                              void* d_out, int out_size, void* d_ws, size_t ws_size,
                              hipStream_t stream) {
  const float* hs  = (const float*)d_in[0];
  const float* rw  = (const float*)d_in[1];
  const int*   sel = (const int*)d_in[2];
  const float* W1  = (const float*)d_in[3];
  const float* W2  = (const float*)d_in[4];
  float* out = (float*)d_out;

  char* ws = (char*)d_ws;
  int*   cnt  = (int*)(ws + 0);
  int*   offs = (int*)(ws + 32);
  int*   tok  = (int*)(ws + 64);
  float* tokw = (float*)(ws + 64 + 4 * NPAIR);
  u16*   Xg   = (u16*)(ws + 65536);
  u16*   gb   = (u16*)(ws + 65536 + (size_t)ROWCAP * HDIM * 2);
  // total ws use: ~62 MB

  hipMemsetAsync(d_out, 0, (size_t)out_size * sizeof(float), stream);
  route_kernel<<<1, 256, 0, stream>>>(rw, sel, cnt, offs, tok, tokw);
  gather_kernel<<<NPAIR, 256, 0, stream>>>(hs, tok, Xg);
  gemm1_kernel<<<dim3(FDIM / 128, NPAIR / 128, NEXP), 256, 0, stream>>>(Xg, W1, gb, cnt, offs);
  gemm2_kernel<<<dim3(HDIM / 128, NPAIR / 128, NEXP), 256, 0, stream>>>(gb, W2, out, cnt, offs, tok, tokw);
}